// Round 11
// baseline (160.675 us; speedup 1.0000x reference)
//
#include <hip/hip_runtime.h>
#include <math.h>

// RiemannianMetric: g[b,s,i,j] = sum_r tanh(x·W[r]+b[r])^2 A[r,i]A[r,j] + lam*I
// B=2 S=1024 DIM=256 RANK=32. Output 537 MB f32 -> store floor ~80us @6.7TB/s.
// R11: single FUSED barrier-free kernel. R9's split cost ~15us K1 serialization +
// 64MB ws round-trip (~10us). Each wave now self-computes: x staged in wave-private
// LDS (wave_barrier only), 32 tanh-dots (2 lanes/rank), sw via shfl, fragments
// built from L1-hot A (160 scalar loads/lane), then R9's validated pipeline:
// 8x{8 MFMA -> swizzled 8KB stage -> nt 512B-segment stores}. Zero __syncthreads.
// Store mode: nt (R9 127 vs R10 plain 132 — settled A/B).

constexpr int DIM = 256;

typedef float f32x4 __attribute__((ext_vector_type(4)));
typedef short s16x8 __attribute__((ext_vector_type(8))); // 8 bf16 = 4 VGPR

static __device__ __forceinline__ unsigned short f2bf(float f) {
    unsigned int u = __builtin_bit_cast(unsigned int, f);
    u = (u + 0x7FFFu + ((u >> 16) & 1u)) >> 16; // RNE
    return (unsigned short)u;
}

__global__ __launch_bounds__(256) void riemannian_metric_kernel(
    const float* __restrict__ x,          // [B*S, DIM]
    const float* __restrict__ A,          // [RANK, DIM]
    const float* __restrict__ log_lambda, // [1]
    const float* __restrict__ W,          // [RANK, DIM]
    const float* __restrict__ bvec,       // [RANK]
    float* __restrict__ out)              // [B*S, DIM, DIM]
{
    __shared__ alignas(16) float stage[4][16 * 128]; // 8KB per wave, 32KB total

    const int tid  = threadIdx.x;
    const int pos  = blockIdx.x;
    const int lane = tid & 63;
    const int rs   = tid >> 6;          // wave: rows 64rs..64rs+63
    const int kg   = lane >> 4, cl = lane & 15;

    float* sbuf = stage[rs];

    // ---- 1. wave-local x staging (1KB into this wave's stage buffer) --------
    *(f32x4*)&sbuf[lane * 4] = *(const f32x4*)(x + (size_t)pos * DIM + lane * 4);
    __builtin_amdgcn_wave_barrier(); // keep compiler from reordering ds ops

    // ---- 2. tanh dots: rank r = lane>>1, half h = lane&1 (128 dims each) ----
    const int r = lane >> 1, h = lane & 1;
    const float* wrow = W + r * DIM + h * 128;
    const float* xrow = sbuf + h * 128;
    float dot = 0.f;
    #pragma unroll
    for (int d = 0; d < 128; d += 4) {
        f32x4 wv4 = *(const f32x4*)(wrow + d);
        f32x4 xx  = *(const f32x4*)(xrow + d); // 2 distinct addrs/instr -> broadcast
        dot = fmaf(wv4.x, xx.x, dot);
        dot = fmaf(wv4.y, xx.y, dot);
        dot = fmaf(wv4.z, xx.z, dot);
        dot = fmaf(wv4.w, xx.w, dot);
    }
    dot += __shfl_xor(dot, 1);
    const float wr = tanhf(dot + bvec[r]); // lane holds w for rank lane>>1

    // ---- 3. distribute: wv[e] = w[kg*8+e] (src lane 16kg+2e) ----------------
    float wv[8];
    #pragma unroll
    for (int e = 0; e < 8; ++e)
        wv[e] = __shfl(wr, 16 * kg + 2 * e);

    // ---- 4. afr: this wave's 4 row-tile frags (u = 4rs+t), from L1-hot A ----
    s16x8 afr[4];
    #pragma unroll
    for (int t = 0; t < 4; ++t) {
        #pragma unroll
        for (int e = 0; e < 8; ++e)
            afr[t][e] = (short)f2bf(wv[e] * A[(kg * 8 + e) * DIM + (4 * rs + t) * 16 + cl]);
    }

    const float lam = expf(log_lambda[0]);
    const bool on_diag_lane = (kg == (cl >> 2));
    const int  diag_slot    = cl & 3;

    const int wbase = cl * 128 + 4 * kg;   // stage write: row=cl, col=uu*16+4kg
    const int wswz  = (cl & 7) << 2;
    const int rrow0 = lane >> 5;           // stage read: 2 rows / instruction
    const int rcol  = (lane & 31) * 4;

    float* gbase = out + (size_t)pos * DIM * DIM;

    // ---- 5. main pipeline: half outer (bfr built once per half) -------------
    #pragma unroll 1
    for (int half = 0; half < 2; ++half) {
        s16x8 bfr[8]; // col-tile frags u = half*8+uu, built from L1-hot A
        #pragma unroll
        for (int uu = 0; uu < 8; ++uu) {
            #pragma unroll
            for (int e = 0; e < 8; ++e)
                bfr[uu][e] = (short)f2bf(wv[e] * A[(kg * 8 + e) * DIM + (half * 8 + uu) * 16 + cl]);
        }
        #pragma unroll 1
        for (int t = 0; t < 4; ++t) {
            #pragma unroll
            for (int uu = 0; uu < 8; ++uu) {
                const int u = half * 8 + uu;
                f32x4 acc = (f32x4)(0.f);
                acc = __builtin_amdgcn_mfma_f32_16x16x32_bf16(bfr[uu], afr[t], acc, 0, 0, 0);
                if (u == rs * 4 + t && on_diag_lane) // diagonal tile of G
                    acc[diag_slot] += lam;
                *(f32x4*)&sbuf[(wbase + uu * 16) ^ wswz] = acc;
            }
            #pragma unroll
            for (int m = 0; m < 8; ++m) {
                const int row = 2 * m + rrow0;
                f32x4 v = *(const f32x4*)&sbuf[(row * 128 + rcol) ^ ((row & 7) << 2)];
                float* gp = gbase + (size_t)(rs * 64 + t * 16 + row) * DIM
                                  + half * 128 + rcol;
                __builtin_nontemporal_store(v, (f32x4*)gp); // 512B contiguous segs
            }
        }
    }
}

extern "C" void kernel_launch(void* const* d_in, const int* in_sizes, int n_in,
                              void* d_out, int out_size, void* d_ws, size_t ws_size,
                              hipStream_t stream) {
    const float* x          = (const float*)d_in[0];
    const float* A          = (const float*)d_in[1];
    const float* log_lambda = (const float*)d_in[2];
    const float* W          = (const float*)d_in[3];
    const float* bvec       = (const float*)d_in[4];
    float* out              = (float*)d_out;

    const int n_pos = in_sizes[0] / DIM; // B*S = 2048
    riemannian_metric_kernel<<<n_pos, 256, 0, stream>>>(x, A, log_lambda, W, bvec, out);
}

// Round 12
// 144.526 us; speedup vs baseline: 1.1117x; 1.1117x over previous
//
#include <hip/hip_runtime.h>
#include <math.h>

// RiemannianMetric: g[b,s,i,j] = sum_r tanh(x·W[r]+b[r])^2 A[r,i]A[r,j] + lam*I
// B=2 S=1024 DIM=256 RANK=32. Output 537 MB f32 -> store floor ~80us @6.7TB/s.
// R12: R9 split + DENSE-WINDOW store sweep. R9's ~1280 uncorrelated blocks x 256KB
// regions = ~320MB scatter window -> DRAM row thrash (~5.1 TB/s). fillBuffer:
// lockstep grid-stride, ~8MB window -> 6.7 TB/s. Mimic it:
//  - K2 grid=512 (all resident, 2 blocks/CU), block sweeps 4 positions in
//    address order: pos = i*512 + sigma(b), sigma = (b&7)*64 + b>>3 (XCD-contig).
//  - waves interleave row-tiles (wave rs owns tile k*4+rs) so each phase k writes
//    one dense 64KB chunk per block (R9: 4 chunks 64KB apart).
//  - K1 same grid/sigma (vt L2 handoff), barrier-free wave-local dots.

constexpr int DIM  = 256;

typedef float f32x4 __attribute__((ext_vector_type(4)));
typedef short s16x8 __attribute__((ext_vector_type(8))); // 8 bf16 = 4 VGPR

static __device__ __forceinline__ unsigned short f2bf(float f) {
    unsigned int u = __builtin_bit_cast(unsigned int, f);
    u = (u + 0x7FFFu + ((u >> 16) & 1u)) >> 16; // RNE
    return (unsigned short)u;
}

// ---------------- Kernel 1: V^T build -> d_ws (barrier-free) -----------------
// layout: vt_g[pos][kg][j][e] (kg=k>>3, e=k&7), u16 bf16. 2048*4*256*8*2B = 32MB.
__global__ __launch_bounds__(256) void build_vt_kernel(
    const float* __restrict__ x, const float* __restrict__ A,
    const float* __restrict__ W, const float* __restrict__ bvec,
    unsigned short* __restrict__ vt_g)
{
    const int tid  = threadIdx.x;
    const int b    = blockIdx.x;
    const int lane = tid & 63;
    const int sigma = (b & 7) * 64 + (b >> 3);

    // each wave computes all 32 dots itself: rank r = lane>>1, half h = lane&1
    const int r = lane >> 1, h = lane & 1;
    const float* wrow = W + r * DIM + h * 128;
    const float  brv  = bvec[r];

    #pragma unroll 1
    for (int i = 0; i < 4; ++i) {
        const int pos = i * 512 + sigma;
        const float* xrow = x + (size_t)pos * DIM + h * 128;
        float dot = 0.f;
        #pragma unroll
        for (int d = 0; d < 128; d += 4) {
            f32x4 wv4 = *(const f32x4*)(wrow + d);
            f32x4 xv4 = *(const f32x4*)(xrow + d);
            dot = fmaf(wv4.x, xv4.x, dot);
            dot = fmaf(wv4.y, xv4.y, dot);
            dot = fmaf(wv4.z, xv4.z, dot);
            dot = fmaf(wv4.w, xv4.w, dot);
        }
        dot += __shfl_xor(dot, 1);
        const float wr_t = tanhf(dot + brv); // lanes {2r,2r+1} hold w[r]

        float wv[32];
        #pragma unroll
        for (int k = 0; k < 32; ++k)
            wv[k] = __shfl(wr_t, 2 * k);

        // thread tid writes column tid of all 4 slabs (coalesced A reads + stores)
        #pragma unroll
        for (int g = 0; g < 4; ++g) {
            s16x8 pk;
            #pragma unroll
            for (int e = 0; e < 8; ++e) {
                const int k = g * 8 + e;
                pk[e] = (short)f2bf(wv[k] * A[k * DIM + tid]);
            }
            *(s16x8*)&vt_g[(((size_t)pos * 4 + g) * DIM + tid) * 8] = pk;
        }
    }
}

// ---------------- Kernel 2: dense-window barrier-free G streamer -------------
__global__ __launch_bounds__(256) void store_g_kernel(
    const unsigned short* __restrict__ vt_g,
    const float* __restrict__ log_lambda,
    float* __restrict__ out)
{
    __shared__ alignas(16) float stage[4][16 * 128]; // 8KB per wave, 32KB total

    const int tid  = threadIdx.x;
    const int b    = blockIdx.x;
    const int lane = tid & 63;
    const int rs   = tid >> 6;
    const int kg   = lane >> 4, cl = lane & 15;
    const int sigma = (b & 7) * 64 + (b >> 3);

    const float lam = expf(log_lambda[0]);
    const bool on_diag_lane = (kg == (cl >> 2));
    const int  diag_slot    = cl & 3;

    float* sbuf = stage[rs];
    const int wbase = cl * 128 + 4 * kg;   // stage write: row=cl, col=uu*16+4kg
    const int wswz  = (cl & 7) << 2;
    const int rrow0 = lane >> 5;           // stage read: 2 rows / instruction
    const int rcol  = (lane & 31) * 4;

    #pragma unroll 1
    for (int i = 0; i < 4; ++i) {
        const int pos = i * 512 + sigma;
        const unsigned short* vbase = vt_g + ((size_t)pos * 4 + kg) * DIM * 8;

        // afr[k]: wave rs owns row-tile T = k*4+rs (tiles interleaved across waves
        // so phase k's block-level writes are one dense 64KB chunk)
        s16x8 afr[4];
        #pragma unroll
        for (int k = 0; k < 4; ++k)
            afr[k] = *(const s16x8*)&vbase[(size_t)((k * 4 + rs) * 16 + cl) * 8];

        float* gbase = out + (size_t)pos * DIM * DIM;

        #pragma unroll 1
        for (int k = 0; k < 4; ++k) {          // phase: rows k*64 .. k*64+63
            #pragma unroll 1
            for (int half = 0; half < 2; ++half) {
                s16x8 bfr[8];
                #pragma unroll
                for (int uu = 0; uu < 8; ++uu) {
                    const int u = half * 8 + uu;
                    bfr[uu] = *(const s16x8*)&vbase[(size_t)(u * 16 + cl) * 8];
                }
                #pragma unroll
                for (int uu = 0; uu < 8; ++uu) {
                    const int u = half * 8 + uu;
                    f32x4 acc = (f32x4)(0.f);
                    acc = __builtin_amdgcn_mfma_f32_16x16x32_bf16(bfr[uu], afr[k], acc, 0, 0, 0);
                    if (u == k * 4 + rs && on_diag_lane) // diagonal tile of G
                        acc[diag_slot] += lam;
                    *(f32x4*)&sbuf[(wbase + uu * 16) ^ wswz] = acc;
                }
                #pragma unroll
                for (int m = 0; m < 8; ++m) {
                    const int row = 2 * m + rrow0;
                    f32x4 v = *(const f32x4*)&sbuf[(row * 128 + rcol) ^ ((row & 7) << 2)];
                    float* gp = gbase + (size_t)(k * 64 + rs * 16 + row) * DIM
                                      + half * 128 + rcol;
                    __builtin_nontemporal_store(v, (f32x4*)gp); // 512B contiguous segs
                }
            }
        }
    }
}

// ---------------- Fallback: R7 monolith (if ws too small) --------------------
__global__ __launch_bounds__(256, 2) void riemannian_metric_fallback(
    const float* __restrict__ x, const float* __restrict__ A,
    const float* __restrict__ log_lambda, const float* __restrict__ W,
    const float* __restrict__ bvec, float* __restrict__ out)
{
    __shared__ float xs[DIM];
    __shared__ float sw[32];
    __shared__ alignas(16) unsigned short vt[4][DIM][8];
    __shared__ alignas(16) float stage[4][16 * 128];

    const int tid  = threadIdx.x;
    const int pos  = blockIdx.x;
    const int lane = tid & 63;
    const int rs   = tid >> 6;

    xs[tid] = x[(size_t)pos * DIM + tid];
    __syncthreads();
    {
        const int r = tid >> 3, seg = tid & 7;
        const f32x4* wr4 = (const f32x4*)(W + r * DIM + seg * 32);
        const f32x4* xr4 = (const f32x4*)(xs + seg * 32);
        float dot = 0.f;
        #pragma unroll
        for (int qq = 0; qq < 8; ++qq) {
            f32x4 wv = wr4[qq], xv = xr4[qq];
            dot = fmaf(wv.x, xv.x, dot);
            dot = fmaf(wv.y, xv.y, dot);
            dot = fmaf(wv.z, xv.z, dot);
            dot = fmaf(wv.w, xv.w, dot);
        }
        dot += __shfl_xor(dot, 1);
        dot += __shfl_xor(dot, 2);
        dot += __shfl_xor(dot, 4);
        if (seg == 0) sw[r] = tanhf(dot + bvec[r]);
    }
    __syncthreads();
    #pragma unroll
    for (int g = 0; g < 4; ++g) {
        s16x8 pk;
        #pragma unroll
        for (int e = 0; e < 8; ++e) {
            const int k = g * 8 + e;
            pk[e] = (short)f2bf(sw[k] * A[k * DIM + tid]);
        }
        *(s16x8*)&vt[g][tid][0] = pk;
    }
    __syncthreads();

    const int kg = lane >> 4, cl = lane & 15;
    s16x8 bfr[16];
    #pragma unroll
    for (int u = 0; u < 16; ++u)
        bfr[u] = *(const s16x8*)&vt[kg][u * 16 + cl][0];
    s16x8 afr[4];
    #pragma unroll
    for (int t = 0; t < 4; ++t)
        afr[t] = *(const s16x8*)&vt[kg][rs * 64 / 16 + t * 16 + cl][0];

    const float lam = expf(log_lambda[0]);
    const bool on_diag_lane = (kg == (cl >> 2));
    const int  diag_slot    = cl & 3;

    float* sbuf = stage[rs];
    const int wbase = cl * 128 + 4 * kg;
    const int wswz  = (cl & 7) << 2;
    const int rrow0 = lane >> 5;
    const int rcol  = (lane & 31) * 4;
    float* gbase = out + (size_t)pos * DIM * DIM;

    #pragma unroll 1
    for (int t = 0; t < 4; ++t) {
        #pragma unroll 1
        for (int half = 0; half < 2; ++half) {
            #pragma unroll
            for (int uu = 0; uu < 8; ++uu) {
                const int u = half * 8 + uu;
                f32x4 acc = (f32x4)(0.f);
                acc = __builtin_amdgcn_mfma_f32_16x16x32_bf16(bfr[u], afr[t], acc, 0, 0, 0);
                if (u == rs * 4 + t && on_diag_lane)
                    acc[diag_slot] += lam;
                *(f32x4*)&sbuf[(wbase + uu * 16) ^ wswz] = acc;
            }
            #pragma unroll
            for (int m = 0; m < 8; ++m) {
                const int row = 2 * m + rrow0;
                f32x4 v = *(const f32x4*)&sbuf[(row * 128 + rcol) ^ ((row & 7) << 2)];
                float* gp = gbase + (size_t)(rs * 64 + t * 16 + row) * DIM
                                  + half * 128 + rcol;
                __builtin_nontemporal_store(v, (f32x4*)gp);
            }
        }
    }
}

extern "C" void kernel_launch(void* const* d_in, const int* in_sizes, int n_in,
                              void* d_out, int out_size, void* d_ws, size_t ws_size,
                              hipStream_t stream) {
    const float* x          = (const float*)d_in[0];
    const float* A          = (const float*)d_in[1];
    const float* log_lambda = (const float*)d_in[2];
    const float* W          = (const float*)d_in[3];
    const float* bvec       = (const float*)d_in[4];
    float* out              = (float*)d_out;

    const int n_pos = in_sizes[0] / DIM; // B*S = 2048
    const size_t vt_bytes = (size_t)n_pos * 4 * DIM * 8 * sizeof(unsigned short); // 32MB

    if (ws_size >= vt_bytes && n_pos == 2048) {
        unsigned short* vt_g = (unsigned short*)d_ws;
        build_vt_kernel<<<512, 256, 0, stream>>>(x, A, W, bvec, vt_g);
        store_g_kernel<<<512, 256, 0, stream>>>(vt_g, log_lambda, out);
    } else {
        riemannian_metric_fallback<<<n_pos, 256, 0, stream>>>(x, A, log_lambda, W, bvec, out);
    }
}

// Round 13
// 117.994 us; speedup vs baseline: 1.3617x; 1.2249x over previous
//
#include <hip/hip_runtime.h>
#include <math.h>

// RiemannianMetric: g[b,s,i,j] = sum_r tanh(x·W[r]+b[r])^2 A[r,i]A[r,j] + lam*I
// B=2 S=1024 DIM=256 RANK=32. Output 537 MB f32 -> store floor ~80us @6.7TB/s.
// R13: R9 split (best, 127us) with ws traffic factored down 64MB -> 0.5MB.
// G = (diag(w^2)A)^T (A): per-position content is only w2[32]! K1 writes
// sw2[2048][32] (256KB) + one-time plain-A bf16 slabs (16KB). K2 is R9's K2
// with identical loop/store structure; frags come from L1-hot ab16; afr scaled
// in-register (32 unpack-mul-cvt per lane per position). One extra bf16 round
// on the row operand only: absmax ~1.5x, still << threshold.

constexpr int DIM = 256;

typedef float f32x4 __attribute__((ext_vector_type(4)));
typedef short s16x8 __attribute__((ext_vector_type(8))); // 8 bf16 = 4 VGPR

static __device__ __forceinline__ unsigned short f2bf(float f) {
    unsigned int u = __builtin_bit_cast(unsigned int, f);
    u = (u + 0x7FFFu + ((u >> 16) & 1u)) >> 16; // RNE
    return (unsigned short)u;
}
static __device__ __forceinline__ float bf2f(unsigned short s) {
    return __builtin_bit_cast(float, (unsigned int)s << 16);
}

// ---------------- Kernel 1: sw2 (tanh^2) + one-time A bf16 slabs -------------
// blocks 0..n_pos-1: sw2[pos][r]. block n_pos: ab16[kg][j][e] = bf16(A[kg*8+e][j]).
__global__ __launch_bounds__(256) void build_sw2_kernel(
    const float* __restrict__ x, const float* __restrict__ A,
    const float* __restrict__ W, const float* __restrict__ bvec,
    float* __restrict__ sw2, unsigned short* __restrict__ ab16, int n_pos)
{
    const int tid = threadIdx.x, b = blockIdx.x;

    if (b == n_pos) { // A conversion: thread j writes 4 slabs (coalesced b128)
        #pragma unroll
        for (int kg = 0; kg < 4; ++kg) {
            s16x8 pk;
            #pragma unroll
            for (int e = 0; e < 8; ++e)
                pk[e] = (short)f2bf(A[(kg * 8 + e) * DIM + tid]);
            *(s16x8*)&ab16[((size_t)kg * DIM + tid) * 8] = pk;
        }
        return;
    }

    __shared__ float xs[DIM];
    xs[tid] = x[(size_t)b * DIM + tid];
    __syncthreads();

    // 8 lanes per rank, shfl-reduced (R9-validated scheme)
    const int r = tid >> 3, seg = tid & 7;
    const f32x4* wr4 = (const f32x4*)(W + r * DIM + seg * 32);
    const f32x4* xr4 = (const f32x4*)(xs + seg * 32);
    float dot = 0.f;
    #pragma unroll
    for (int qq = 0; qq < 8; ++qq) {
        f32x4 wv = wr4[qq], xv = xr4[qq];
        dot = fmaf(wv.x, xv.x, dot);
        dot = fmaf(wv.y, xv.y, dot);
        dot = fmaf(wv.z, xv.z, dot);
        dot = fmaf(wv.w, xv.w, dot);
    }
    dot += __shfl_xor(dot, 1);
    dot += __shfl_xor(dot, 2);
    dot += __shfl_xor(dot, 4);
    if (seg == 0) {
        float m = tanhf(dot + bvec[r]);
        sw2[(size_t)b * 32 + r] = m * m;
    }
}

// ---------------- Kernel 2: barrier-free G streamer (R9 structure) -----------
__global__ __launch_bounds__(256) void store_g_kernel(
    const unsigned short* __restrict__ ab16, // [4][256][8] plain A bf16
    const float* __restrict__ sw2,           // [n_pos][32]
    const float* __restrict__ log_lambda,
    float* __restrict__ out)
{
    __shared__ alignas(16) float stage[4][16 * 128]; // 8KB per wave, 32KB total

    const int tid  = threadIdx.x;
    const int pos  = blockIdx.x;
    const int lane = tid & 63;
    const int rs   = tid >> 6;          // wave: rows 64rs..64rs+63
    const int kg   = lane >> 4, cl = lane & 15;

    // position-independent base: this lane's kg-slab of plain A bf16 (L1-hot 16KB)
    const unsigned short* abase = ab16 + (size_t)kg * DIM * 8;

    // per-position scale w2[kg*8+e] (L2-resident 256KB)
    const float* w2p = sw2 + (size_t)pos * 32 + kg * 8;
    f32x4 w2lo = *(const f32x4*)w2p;
    f32x4 w2hi = *(const f32x4*)(w2p + 4);
    float w2v[8] = {w2lo.x, w2lo.y, w2lo.z, w2lo.w, w2hi.x, w2hi.y, w2hi.z, w2hi.w};

    // afr: scaled row-tile frags (only per-position VALU work: 32 unpack-mul-cvt)
    s16x8 afr[4];
    #pragma unroll
    for (int t = 0; t < 4; ++t) {
        s16x8 ar = *(const s16x8*)&abase[(size_t)((4 * rs + t) * 16 + cl) * 8];
        #pragma unroll
        for (int e = 0; e < 8; ++e)
            afr[t][e] = (short)f2bf(w2v[e] * bf2f((unsigned short)ar[e]));
    }

    const float lam = expf(log_lambda[0]);
    const bool on_diag_lane = (kg == (cl >> 2));
    const int  diag_slot    = cl & 3;

    float* sbuf = stage[rs];
    const int wbase = cl * 128 + 4 * kg;   // stage write: row=cl, col=uu*16+4kg
    const int wswz  = (cl & 7) << 2;
    const int rrow0 = lane >> 5;           // stage read: 2 rows / instruction
    const int rcol  = (lane & 31) * 4;

    float* gbase = out + (size_t)pos * DIM * DIM;

    #pragma unroll 1
    for (int t = 0; t < 4; ++t) {
        #pragma unroll 1
        for (int half = 0; half < 2; ++half) {
            s16x8 bfr[8]; // plain-A col-tile frags (L1-hot, no per-position work)
            #pragma unroll
            for (int uu = 0; uu < 8; ++uu) {
                const int u = half * 8 + uu;
                bfr[uu] = *(const s16x8*)&abase[(size_t)(u * 16 + cl) * 8];
            }
            #pragma unroll
            for (int uu = 0; uu < 8; ++uu) {
                const int u = half * 8 + uu;
                f32x4 acc = (f32x4)(0.f);
                acc = __builtin_amdgcn_mfma_f32_16x16x32_bf16(bfr[uu], afr[t], acc, 0, 0, 0);
                if (u == rs * 4 + t && on_diag_lane) // diagonal tile of G
                    acc[diag_slot] += lam;
                *(f32x4*)&sbuf[(wbase + uu * 16) ^ wswz] = acc;
            }
            #pragma unroll
            for (int m = 0; m < 8; ++m) {
                const int row = 2 * m + rrow0;
                f32x4 v = *(const f32x4*)&sbuf[(row * 128 + rcol) ^ ((row & 7) << 2)];
                float* gp = gbase + (size_t)(rs * 64 + t * 16 + row) * DIM
                                  + half * 128 + rcol;
                __builtin_nontemporal_store(v, (f32x4*)gp); // 512B contiguous segs
            }
        }
    }
}

// ---------------- Fallback monolith (R7-validated) ---------------------------
__global__ __launch_bounds__(256, 2) void riemannian_metric_fallback(
    const float* __restrict__ x, const float* __restrict__ A,
    const float* __restrict__ log_lambda, const float* __restrict__ W,
    const float* __restrict__ bvec, float* __restrict__ out)
{
    __shared__ float xs[DIM];
    __shared__ float sw[32];
    __shared__ alignas(16) unsigned short vt[4][DIM][8];
    __shared__ alignas(16) float stage[4][16 * 128];

    const int tid  = threadIdx.x;
    const int pos  = blockIdx.x;
    const int lane = tid & 63;
    const int rs   = tid >> 6;

    xs[tid] = x[(size_t)pos * DIM + tid];
    __syncthreads();
    {
        const int r = tid >> 3, seg = tid & 7;
        const f32x4* wr4 = (const f32x4*)(W + r * DIM + seg * 32);
        const f32x4* xr4 = (const f32x4*)(xs + seg * 32);
        float dot = 0.f;
        #pragma unroll
        for (int qq = 0; qq < 8; ++qq) {
            f32x4 wv = wr4[qq], xv = xr4[qq];
            dot = fmaf(wv.x, xv.x, dot);
            dot = fmaf(wv.y, xv.y, dot);
            dot = fmaf(wv.z, xv.z, dot);
            dot = fmaf(wv.w, xv.w, dot);
        }
        dot += __shfl_xor(dot, 1);
        dot += __shfl_xor(dot, 2);
        dot += __shfl_xor(dot, 4);
        if (seg == 0) sw[r] = tanhf(dot + bvec[r]);
    }
    __syncthreads();
    #pragma unroll
    for (int g = 0; g < 4; ++g) {
        s16x8 pk;
        #pragma unroll
        for (int e = 0; e < 8; ++e) {
            const int k = g * 8 + e;
            pk[e] = (short)f2bf(sw[k] * A[k * DIM + tid]);
        }
        *(s16x8*)&vt[g][tid][0] = pk;
    }
    __syncthreads();

    const int kg = lane >> 4, cl = lane & 15;
    s16x8 bfr[16];
    #pragma unroll
    for (int u = 0; u < 16; ++u)
        bfr[u] = *(const s16x8*)&vt[kg][u * 16 + cl][0];
    s16x8 afr[4];
    #pragma unroll
    for (int t = 0; t < 4; ++t)
        afr[t] = *(const s16x8*)&vt[kg][rs * 64 + t * 16 + cl][0];

    const float lam = expf(log_lambda[0]);
    const bool on_diag_lane = (kg == (cl >> 2));
    const int  diag_slot    = cl & 3;

    float* sbuf = stage[rs];
    const int wbase = cl * 128 + 4 * kg;
    const int wswz  = (cl & 7) << 2;
    const int rrow0 = lane >> 5;
    const int rcol  = (lane & 31) * 4;
    float* gbase = out + (size_t)pos * DIM * DIM;

    #pragma unroll 1
    for (int t = 0; t < 4; ++t) {
        #pragma unroll 1
        for (int half = 0; half < 2; ++half) {
            #pragma unroll
            for (int uu = 0; uu < 8; ++uu) {
                const int u = half * 8 + uu;
                f32x4 acc = (f32x4)(0.f);
                acc = __builtin_amdgcn_mfma_f32_16x16x32_bf16(bfr[u], afr[t], acc, 0, 0, 0);
                if (u == rs * 4 + t && on_diag_lane)
                    acc[diag_slot] += lam;
                *(f32x4*)&sbuf[(wbase + uu * 16) ^ wswz] = acc;
            }
            #pragma unroll
            for (int m = 0; m < 8; ++m) {
                const int row = 2 * m + rrow0;
                f32x4 v = *(const f32x4*)&sbuf[(row * 128 + rcol) ^ ((row & 7) << 2)];
                float* gp = gbase + (size_t)(rs * 64 + t * 16 + row) * DIM
                                  + half * 128 + rcol;
                __builtin_nontemporal_store(v, (f32x4*)gp);
            }
        }
    }
}

extern "C" void kernel_launch(void* const* d_in, const int* in_sizes, int n_in,
                              void* d_out, int out_size, void* d_ws, size_t ws_size,
                              hipStream_t stream) {
    const float* x          = (const float*)d_in[0];
    const float* A          = (const float*)d_in[1];
    const float* log_lambda = (const float*)d_in[2];
    const float* W          = (const float*)d_in[3];
    const float* bvec       = (const float*)d_in[4];
    float* out              = (float*)d_out;

    const int n_pos = in_sizes[0] / DIM; // B*S = 2048
    // ws layout: ab16 (16KB) | sw2 (n_pos*32*4 B)
    const size_t ab16_bytes = (size_t)4 * DIM * 8 * sizeof(unsigned short);
    const size_t need = ab16_bytes + (size_t)n_pos * 32 * sizeof(float);

    if (ws_size >= need) {
        unsigned short* ab16 = (unsigned short*)d_ws;
        float* sw2 = (float*)((char*)d_ws + ab16_bytes);
        build_sw2_kernel<<<n_pos + 1, 256, 0, stream>>>(x, A, W, bvec, sw2, ab16, n_pos);
        store_g_kernel<<<n_pos, 256, 0, stream>>>(ab16, sw2, log_lambda, out);
    } else {
        riemannian_metric_fallback<<<n_pos, 256, 0, stream>>>(x, A, log_lambda, W, bvec, out);
    }
}